// Round 7
// baseline (517.700 us; speedup 1.0000x reference)
//
#include <hip/hip_runtime.h>

// GAT layer, N=8192, F_IN=512, F_OUT=256. ALL tensors f32; adj int32.
// out = softmax_row(mask(leaky(s1_i+s2_j))) @ h, h = X@W, s{1,2} = h_f32@a{1,2}.
//
// R16 -> R17:
//  * R16 never ran: static LDS was ~101 KB (>64 KB limit) -> launch/compile
//    failure. Same theory, budgeted: P ring 4->2 (R15 proved ring neutral),
//    drop s2 LDS preload (s2 is L1-broadcast, keep 2-deep reg prefetch),
//    keep adj->1-bit-mask LDS pre-loop (33.3 KB). Total LDS 50.8 KB.
//  * Loop skeleton = R13 verbatim (109us proven): B dbuf 1 ahead, lgkm-only
//    barrier, setprio around MFMA. Loop global traffic 96->64.5 KB/iter/CU,
//    VMEM instr -38% (adj's 2 ix4/thread/iter removed from the loop).
//  * Numerics bit-identical: absmax canary 0.0078125.

typedef __attribute__((ext_vector_type(8))) short bf16x8;
typedef __attribute__((ext_vector_type(4))) float fx4;
typedef __attribute__((ext_vector_type(4))) int ix4;
typedef __attribute__((ext_vector_type(2))) unsigned int ux2;

#define NN 8192
#define FIN 512
#define FOUT 256
#define PS 136     // LDS P row stride (shorts); 272B stride -> conflict-free b128
#define AROWS 32   // attn rows per block
#define MPAD 260   // mask row stride (dwords): rotates banks for broadcast reads

__device__ __forceinline__ unsigned short f2bf(float f) {
    unsigned int x = __float_as_uint(f);
    x += 0x7fffu + ((x >> 16) & 1u);
    return (unsigned short)(x >> 16);
}
__device__ __forceinline__ bf16x8 pack8(fx4 a, fx4 b) {
    bf16x8 r;
    r[0] = (short)f2bf(a[0]); r[1] = (short)f2bf(a[1]);
    r[2] = (short)f2bf(a[2]); r[3] = (short)f2bf(a[3]);
    r[4] = (short)f2bf(b[0]); r[5] = (short)f2bf(b[1]);
    r[6] = (short)f2bf(b[2]); r[7] = (short)f2bf(b[3]);
    return r;
}

// ---------- kernel 0: WTt[((k>>5)*256+c)*32 + (k&31)] = bf16(W[k][c]) ----------
__global__ void wt_kernel(const float* __restrict__ W,
                          unsigned short* __restrict__ WTt) {
    const int c = threadIdx.x;
    const int k = blockIdx.x;
    WTt[((size_t)(k >> 5) * 256 + c) * 32 + (k & 31)] = f2bf(W[k * FOUT + c]);
}

// ---------- kernel 1: h-tile (MFMA) + fused s1/s2 ----------
// 512 blocks x 16 rows. MFMA 16x16x32: A[m=l&15][k=q*8+j], B[k=q*8+j][n=l&15],
// D: col=l&15, row=q*4+r.
__global__ __launch_bounds__(256) void prep_kernel(
    const float* __restrict__ X,              // 8192x512 f32
    const unsigned short* __restrict__ WTt,   // tiled 256x512 bf16
    const float* __restrict__ A,              // 512 f32 (a1|a2)
    unsigned short* __restrict__ hTt,         // tiled 256x8192 bf16
    float* __restrict__ s1, float* __restrict__ s2)
{
    __shared__ float s1sh[4][16], s2sh[4][16];
    const int tid = threadIdx.x;

    const int w = tid >> 6, l = tid & 63, q = l >> 4, lr = l & 15;
    const int r0 = blockIdx.x * 16;
    const int cbase = w * 64;
    fx4 acc[4] = {};

    for (int kb = 0; kb < FIN; kb += 32) {
        const float* xp = X + (size_t)(r0 + lr) * FIN + kb + q * 8;
        bf16x8 a0 = pack8(*(const fx4*)xp, *(const fx4*)(xp + 4));
#pragma unroll
        for (int tc = 0; tc < 4; ++tc) {
            bf16x8 b = *(const bf16x8*)(WTt + ((size_t)(kb >> 5) * 256 + cbase + tc * 16 + lr) * 32 + q * 8);
            acc[tc] = __builtin_amdgcn_mfma_f32_16x16x32_bf16(a0, b, acc[tc], 0, 0, 0);
        }
    }

    // tiled hTt write
    const int jb = r0 >> 5, jo = (r0 & 31) + q * 4;
#pragma unroll
    for (int tc = 0; tc < 4; ++tc) {
        const int c = cbase + tc * 16 + lr;
        ux2 hp;
        hp.x = (unsigned)f2bf(acc[tc][0]) | ((unsigned)f2bf(acc[tc][1]) << 16);
        hp.y = (unsigned)f2bf(acc[tc][2]) | ((unsigned)f2bf(acc[tc][3]) << 16);
        *(ux2*)(hTt + ((size_t)jb * 256 + c) * 32 + jo) = hp;
    }

    // fused s1/s2 from f32 accumulators
    float p1[4] = {}, p2[4] = {};
#pragma unroll
    for (int tc = 0; tc < 4; ++tc) {
        const int c = cbase + tc * 16 + lr;
        const float a1v = A[c], a2v = A[FOUT + c];
#pragma unroll
        for (int r = 0; r < 4; ++r) {
            p1[r] += acc[tc][r] * a1v;
            p2[r] += acc[tc][r] * a2v;
        }
    }
#pragma unroll
    for (int r = 0; r < 4; ++r) {
#pragma unroll
        for (int off = 1; off < 16; off <<= 1) {
            p1[r] += __shfl_xor(p1[r], off);
            p2[r] += __shfl_xor(p2[r], off);
        }
        if (lr == 0) { s1sh[w][q * 4 + r] = p1[r]; s2sh[w][q * 4 + r] = p2[r]; }
    }
    __syncthreads();
    if (tid < 16) {
        s1[r0 + tid] = s1sh[0][tid] + s1sh[1][tid] + s1sh[2][tid] + s1sh[3][tid];
        s2[r0 + tid] = s2sh[0][tid] + s2sh[1][tid] + s2sh[2][tid] + s2sh[3][tid];
    }
}

// ---------- kernel 2: fused masked-softmax @ h, f32 out ----------
// Grid 256 x 512 thr. 32 rows/block; wave w owns cols w*32..+31.
// Pre-loop: adj slice (1 MB, nt) -> 1-bit mask in LDS (32x260 dwords).
// Main loop global traffic: B-frags (hTt, L2-resident, dbuf 1 ahead) + tiny
// s2 broadcast loads (2-deep reg prefetch). P (32x128 bf16) double-buffered;
// in-loop barrier drains ONLY lgkmcnt so global prefetches stay in flight.
__global__ __launch_bounds__(512) void attn_kernel(
    const int* __restrict__ adj,             // 8192 x 8192 i32
    const unsigned short* __restrict__ hTt,  // tiled 256 x 8192 bf16
    const float* __restrict__ s1,
    const float* __restrict__ s2,
    float* __restrict__ out)                 // 8192 x 256 f32
{
    __shared__ unsigned short P[2][AROWS * PS];   // 17.4 KB
    __shared__ unsigned int mlds[AROWS * MPAD];   // 33.3 KB 1-bit mask
    __shared__ float dsh[AROWS];                  // total ~50.8 KB

    const int tid = threadIdx.x;
    const int r0 = blockIdx.x * AROWS;

    // ---- pre-loop: adj slice -> 1-bit mask (R10 bit-math), nt loads ----
#pragma unroll 2
    for (int s = 0; s < 16; ++s) {
        const int g = s * 512 + tid;          // 0..8191 -> (row, dword)
        const int row = g >> 8, dw = g & 255;
        const int* base = adj + (size_t)(r0 + row) * NN + dw * 32;
        ix4 v[8];
#pragma unroll
        for (int k = 0; k < 8; ++k)
            v[k] = __builtin_nontemporal_load((const ix4*)(base + k * 4));
        unsigned int m = 0;
#pragma unroll
        for (int k = 0; k < 8; ++k)
#pragma unroll
            for (int j = 0; j < 4; ++j)
                m |= (v[k][j] != 0 ? 1u : 0u) << (k * 4 + j);
        mlds[row * MPAD + dw] = m;
    }
    __syncthreads();

    // P-generation role: thread -> (row, 8-col group)
    const int prow = tid >> 4;                 // 0..31
    const int pq = tid & 15;                   // cols pq*8..+7
    const float s1v = s1[r0 + prow];
    const int mshift = (pq & 3) * 8;
    float denp = 0.f;

    // MFMA role
    const int w = tid >> 6, l = tid & 63, q = l >> 4, lr = l & 15;
    const int cbase = w * 32;
    fx4 acc[2][2] = {};

    struct LSet { fx4 s2a, s2b; };             // s2 only (adj now in LDS)
    LSet LA, LB;
    bf16x8 B0[4][2], B1[4][2];

    auto loadS = [&](int kt, LSet& L) {
        L.s2a = *(const fx4*)(s2 + kt * 128 + pq * 8);
        L.s2b = *(const fx4*)(s2 + kt * 128 + pq * 8 + 4);
    };
    auto calcP = [&](int b, int kt, const LSet& L) {   // writes P[b]
        const unsigned int mval = mlds[prow * MPAD + kt * 4 + (pq >> 2)];
        const unsigned int mbyte = (mval >> mshift) & 0xFFu;
        bf16x8 pv;
#pragma unroll
        for (int j = 0; j < 8; ++j) {
            const float s2j = (j < 4) ? L.s2a[j] : L.s2b[j - 4];
            float t = s1v + s2j;
            float e = fmaxf(t, 0.2f * t);      // leaky_relu, alpha=0.2
            e = fminf(e, 30.f);                // overflow guard (inactive)
            const float p = ((mbyte >> j) & 1u) ? __expf(e) : 0.f;
            denp += p;
            pv[j] = (short)f2bf(p);
        }
        *(bf16x8*)(&P[b][prow * PS + pq * 8]) = pv;   // 16B store
    };
    auto loadB = [&](int it, bf16x8 (&B)[4][2]) {
#pragma unroll
        for (int ks = 0; ks < 4; ++ks)
#pragma unroll
            for (int tc = 0; tc < 2; ++tc)
                B[ks][tc] = *(const bf16x8*)(hTt + ((size_t)(it * 4 + ks) * 256 + cbase + tc * 16 + lr) * 32 + q * 8);
    };

    // LDS-only barrier: ds ops drained (lgkmcnt), global loads stay in flight.
    auto ldsBarrier = [&]() {
        asm volatile("s_waitcnt lgkmcnt(0)" ::: "memory");
        __builtin_amdgcn_s_barrier();
    };

    const int ITERS = NN / 128;   // 64
    loadS(0, LA);
    calcP(0, 0, LA);
    loadS(1, LA);
    loadB(0, B0);
    ldsBarrier();

    auto body = [&](int it, bf16x8 (&Bc)[4][2], bf16x8 (&Bn)[4][2],
                    LSet& Lc, LSet& Ln) {
        if (it + 1 < ITERS) loadB(it + 1, Bn);     // in flight across barrier
        if (it + 2 < ITERS) loadS(it + 2, Ln);     // 2-deep s2 prefetch
        const unsigned short* Pb = P[it & 1];
        bf16x8 af0[4], af1[4];
#pragma unroll
        for (int ks = 0; ks < 4; ++ks) {
            af0[ks] = *(const bf16x8*)(Pb + lr * PS + ks * 32 + q * 8);
            af1[ks] = *(const bf16x8*)(Pb + (16 + lr) * PS + ks * 32 + q * 8);
        }
        __builtin_amdgcn_s_setprio(1);
#pragma unroll
        for (int ks = 0; ks < 4; ++ks)
#pragma unroll
            for (int tc = 0; tc < 2; ++tc) {
                acc[0][tc] = __builtin_amdgcn_mfma_f32_16x16x32_bf16(af0[ks], Bc[ks][tc], acc[0][tc], 0, 0, 0);
                acc[1][tc] = __builtin_amdgcn_mfma_f32_16x16x32_bf16(af1[ks], Bc[ks][tc], acc[1][tc], 0, 0, 0);
            }
        __builtin_amdgcn_s_setprio(0);
        if (it + 1 < ITERS) calcP((it + 1) & 1, it + 1, Lc);
        ldsBarrier();
    };

    for (int it = 0; it < ITERS; it += 2) {
        body(it, B0, B1, LA, LB);
        body(it + 1, B1, B0, LB, LA);
    }

    // den: reduce over the 16 lanes sharing a row
    float v = denp;
    v += __shfl_xor(v, 1);
    v += __shfl_xor(v, 2);
    v += __shfl_xor(v, 4);
    v += __shfl_xor(v, 8);
    if (pq == 0) dsh[prow] = v;
    __syncthreads();

#pragma unroll
    for (int mg = 0; mg < 2; ++mg) {
#pragma unroll
        for (int r = 0; r < 4; ++r) {
            const int row = mg * 16 + q * 4 + r;
            const float dinv = 1.0f / fmaxf(dsh[row], 1e-30f);
#pragma unroll
            for (int tc = 0; tc < 2; ++tc) {
                out[(size_t)(r0 + row) * FOUT + cbase + tc * 16 + lr] = acc[mg][tc][r] * dinv;
            }
        }
    }
}

extern "C" void kernel_launch(void* const* d_in, const int* in_sizes, int n_in,
                              void* d_out, int out_size, void* d_ws, size_t ws_size,
                              hipStream_t stream) {
    const float *X = nullptr, *W = nullptr, *A = nullptr;
    const int* adj = nullptr;
    for (int i = 0; i < n_in; ++i) {
        switch (in_sizes[i]) {
            case NN * FIN:   X = (const float*)d_in[i]; break;
            case FIN * FOUT: W = (const float*)d_in[i]; break;
            case 2 * FOUT:   A = (const float*)d_in[i]; break;
            case NN * NN:    adj = (const int*)d_in[i]; break;
        }
    }
    if (!X) X = (const float*)d_in[0];
    if (!W) W = (const float*)d_in[1];
    if (!A) A = (const float*)d_in[2];
    if (!adj) adj = (const int*)d_in[3];
    float* out = (float*)d_out;

    // ws layout (subset of the 1 GiB ws):
    char* ws = (char*)d_ws;
    float* s1 = (float*)ws;                                 // 32 KB
    float* s2 = (float*)(ws + 32768);                       // 32 KB
    unsigned short* WTt = (unsigned short*)(ws + 98304);    // 256 KB
    unsigned short* hTt = (unsigned short*)(ws + 360448);   // 4 MB

    wt_kernel<<<512, 256, 0, stream>>>(W, WTt);
    prep_kernel<<<512, 256, 0, stream>>>(X, WTt, A, hTt, s1, s2);
    attn_kernel<<<NN / AROWS, 512, 0, stream>>>(adj, hTt, s1, s2, out);
}